// Round 12
// baseline (471.648 us; speedup 1.0000x reference)
//
#include <hip/hip_runtime.h>
#include <math.h>

namespace {

constexpr int BN = 16;      // batch
constexpr int CN = 64;      // input channels
constexpr int HN = 128;     // hidden
constexpr int GN = 64;      // grid dims
constexpr int KH = 2 * HN;          // 256
constexpr int KTOT = KH + CN;       // 320
constexpr int LDSK = 328;           // Hc stride (fp16 elems)
constexpr int GBS2 = 260;           // gb stride (fp32)

typedef _Float16 half8 __attribute__((ext_vector_type(8)));
typedef float float4v __attribute__((ext_vector_type(4)));
typedef unsigned long long u64;

// fast transcendentals (v_exp_f32 based) for the sweep epilogue
__device__ __forceinline__ float fsig(float z) {
    return 1.f / (1.f + __expf(-z));
}
__device__ __forceinline__ float ftanh(float z) {
    return 1.f - 2.f / (__expf(2.f * z) + 1.f);   // exact at 0, saturates to +-1
}

// ---------------- merged prep: wprep (blk<640) + xconv (blk>=640) -------------
__global__ __launch_bounds__(256) void prep_kernel(
    const float* __restrict__ Wih,    // [2,512,64]
    const float* __restrict__ Whh,    // [2,512,256]
    _Float16* __restrict__ wf,        // [640][64][8]
    const float* __restrict__ x,      // [B,C,G,G]
    _Float16* __restrict__ xb)        // [G,G,B,C]
{
    const int blk = blockIdx.x;
    if (blk < 640) {
        const int t = threadIdx.x;
        if (t < 64) {
            const int nt = blk / 10, ks = blk - nt * 10;
            const int lane = t;
            const int dd = nt >> 5;
            const int gr = (nt & 31) * 16 + (lane & 15);    // gate row 0..511
            const int k0 = ks * 32 + (lane >> 4) * 8;
            _Float16* dst = wf + ((size_t)blk * 64 + lane) * 8;
            #pragma unroll
            for (int e = 0; e < 8; ++e) {
                const int k = k0 + e;
                const float v = (k < KH)
                    ? Whh[((size_t)(dd * 512 + gr)) * KH + k]
                    : Wih[((size_t)(dd * 512 + gr)) * CN + (k - KH)];
                dst[e] = (_Float16)v;
            }
        }
    } else {
        __shared__ float tile[CN][GN + 1];
        const int bb = blk - 640;
        const int b = bb >> 6;
        const int i = bb & 63;
        const int t = threadIdx.x;
        const int tj = t & 63, tc = t >> 6;
        for (int c0 = 0; c0 < CN; c0 += 4) {
            const int c = c0 + tc;
            tile[c][tj] = x[((size_t)(b * CN + c) * GN + i) * GN + tj];
        }
        __syncthreads();
        const int wc = t & 63, wj = t >> 6;
        for (int j0 = 0; j0 < GN; j0 += 4) {
            const int j = j0 + wj;
            xb[((size_t)(i * GN + j) * BN + b) * CN + wc] = (_Float16)tile[wc][j];
        }
    }
}

// ---------------- post-pass: hbuf [G,G,B,256] fp16 -> out [B,256,G,G] (r7) ----
__global__ __launch_bounds__(256) void out_kernel(
    const _Float16* __restrict__ hbuf, float* __restrict__ out)
{
    const int b = blockIdx.x >> 6;
    const int i = blockIdx.x & 63;
    const int t = threadIdx.x;          // channel 0..255
    float* op = out + ((size_t)(b * KH + t)) * (GN * GN) + (size_t)i * GN;
    const _Float16* hp = hbuf + ((size_t)i * GN * BN + b) * KH + t;
    #pragma unroll 4
    for (int j = 0; j < GN; ++j)
        op[j] = (float)hp[(size_t)j * (BN * KH)];
}

// ---------------- row-quad persistent sweep (r10/r11-proven structure) --------
// 256 blocks x 512 threads = 64 rows x 4 slices (dd, ub). Block owns row i.
// R12 chain surgery: (1) split-K MFMA: part1 (h1+x, 12 MFMA) runs while the
// h2 global loads are in flight; deferred h2 ds_write + B1b + part2 (8 MFMA).
// (2) per-wave flag increments after per-wave vmcnt drain (target 2 -> 16),
// trailing block barrier removed (next step's B1a provides LDS ordering).
// (3) fast __expf-based sigmoid/tanh in the epilogue.
template <bool USE_XB>
__global__ __launch_bounds__(512, 1) void grid_lstm_rowq(
    const _Float16* __restrict__ wf,   // [640][64][8]
    const _Float16* __restrict__ xb,   // [G,G,B,C] (USE_XB)
    const float* __restrict__ x,       // [B,C,G,G] (!USE_XB)
    const float* __restrict__ bih,     // [2,512]
    const float* __restrict__ bhh,     // [2,512]
    _Float16* __restrict__ hbuf,       // [G,G,B,256]
    float* __restrict__ cmail,         // [2][G(j)][B][H] fp32 ring over i
    int* __restrict__ flag1,           // [G,G] h1 ready (target 16)
    int* __restrict__ flag2)           // [G,G] h2 ready (target 16)
{
    __shared__ __align__(16) _Float16 Wl2[16 * 8 * 64 * 8];  // 131072 B
    __shared__ __align__(16) _Float16 Hc[BN * LDSK];         // 10496 B
    __shared__ __align__(16) float gb[BN * GBS2];            // 16640 B
    __shared__ float blds[256];                              // 1024 B

    const int blk = blockIdx.x;
    const int i  = blk & 63;              // grid row (row-quad shares XCD)
    const int s  = blk >> 6;
    const int dd = s >> 1;                // grid-LSTM dim
    const int ub = s & 1;                 // unit half

    const int t = threadIdx.x;
    const int lane = t & 63;
    const int wv = t >> 6;                // wave 0..7
    const int l15 = lane & 15;
    const int l4 = lane >> 4;

    const half8* wfv = (const half8*)wf;
    half8* wl2v = (half8*)Wl2;

    // --- one-time: stage Whh fragments (ks 0..7) into LDS, fragment-major ---
    for (int e = t; e < 16 * 8 * 64; e += 512) {
        const int ln = e & 63, ks = (e >> 6) & 7, tl = e >> 9;
        const int q = tl >> 2, w = tl & 3;
        const int nt = dd * 32 + q * 8 + ub * 4 + w;
        wl2v[e] = wfv[(size_t)(nt * 10 + ks) * 64 + ln];
    }
    // --- one-time: Wih fragments (ks 8,9) into registers ---
    const int tlA = 2 * wv, tlB = 2 * wv + 1;
    const int ntA = dd * 32 + (tlA >> 2) * 8 + ub * 4 + (tlA & 3);
    const int ntB = dd * 32 + (tlB >> 2) * 8 + ub * 4 + (tlB & 3);
    const half8 wA8 = wfv[(size_t)(ntA * 10 + 8) * 64 + lane];
    const half8 wA9 = wfv[(size_t)(ntA * 10 + 9) * 64 + lane];
    const half8 wB8 = wfv[(size_t)(ntB * 10 + 8) * 64 + lane];
    const half8 wB9 = wfv[(size_t)(ntB * 10 + 9) * 64 + lane];
    // --- one-time: biases (local col = q*64 + uu) ---
    if (t < 256) {
        const int q = t >> 6, uu = t & 63;
        const int gr = dd * 512 + q * 128 + ub * 64 + uu;
        blds[t] = bih[gr] + bhh[gr];
    }
    // staging role (split): sb = batch, sk = 16B chunk within 128 fp16
    const int sb = (t & 255) >> 4;
    const int sk = (t & 15);
    const bool roleH1 = (t < 256);
    // epilogue role: batch eb, unit pair u2, u2+1
    const int eb = t >> 5;
    const int u2 = (t & 31) * 2;
    float c2r0 = 0.f, c2r1 = 0.f;        // dim1 c-state (dd==1 blocks)

    // --- prologue: stage x(i,0) ---
    if (USE_XB) {
        if (t < 256)
            *(u64*)(&Hc[(t >> 4) * LDSK + KH + (t & 15) * 4]) =
                *(const u64*)(xb + ((size_t)(i * GN)) * (BN * CN)
                              + (t >> 4) * CN + (t & 15) * 4);
    } else {
        #pragma unroll
        for (int r = 0; r < 2; ++r) {
            const int e = t + r * 512;
            const int b2 = e >> 6, c = e & 63;
            Hc[b2 * LDSK + KH + c] =
                (_Float16)x[(size_t)(b2 * 64 + c) * 4096 + i * 64];
        }
    }
    __syncthreads();

    for (int j = 0; j < GN; ++j) {
        const int cellidx = i * GN + j;

        // --- split-role staging: h1 written now; h2 loads issued, write deferred
        u64 q0 = 0, q1 = 0;
        if (roleH1) {
            if (i > 0) {
                const int* fp = flag1 + cellidx - GN;
                int it = 0;
                while (__hip_atomic_load(fp, __ATOMIC_RELAXED,
                                         __HIP_MEMORY_SCOPE_AGENT) < 16) {
                    __builtin_amdgcn_s_sleep(1);
                    if (++it > (1 << 24)) break;   // failsafe
                }
                const u64* src = (const u64*)(hbuf
                    + ((size_t)(cellidx - GN)) * (BN * KH) + sb * KH + sk * 8);
                q0 = __hip_atomic_load(src, __ATOMIC_RELAXED,
                                       __HIP_MEMORY_SCOPE_AGENT);
                q1 = __hip_atomic_load(src + 1, __ATOMIC_RELAXED,
                                       __HIP_MEMORY_SCOPE_AGENT);
            }
            *(u64*)(&Hc[sb * LDSK + sk * 8]) = q0;
            *(u64*)(&Hc[sb * LDSK + sk * 8 + 4]) = q1;
        } else {
            if (j > 0) {
                const int* fp = flag2 + cellidx - 1;
                int it = 0;
                while (__hip_atomic_load(fp, __ATOMIC_RELAXED,
                                         __HIP_MEMORY_SCOPE_AGENT) < 16) {
                    __builtin_amdgcn_s_sleep(1);
                    if (++it > (1 << 24)) break;
                }
                const u64* src = (const u64*)(hbuf
                    + ((size_t)(cellidx - 1)) * (BN * KH)
                    + sb * KH + HN + sk * 8);
                q0 = __hip_atomic_load(src, __ATOMIC_RELAXED,
                                       __HIP_MEMORY_SCOPE_AGENT);
                q1 = __hip_atomic_load(src + 1, __ATOMIC_RELAXED,
                                       __HIP_MEMORY_SCOPE_AGENT);
                // ds_write deferred to after MFMA part-1 (loads fly under it)
            } else {
                *(u64*)(&Hc[sb * LDSK + HN + sk * 8]) = 0ull;
                *(u64*)(&Hc[sb * LDSK + HN + sk * 8 + 4]) = 0ull;
            }
        }
        __syncthreads();   // B1a: h1 + x (+ h2 zeros at j==0) staged

        // --- MFMA part-1: K = h1 (ks0..3) + x (ks8,9), 12 MFMA ---
        float4v acc0 = {0.f, 0.f, 0.f, 0.f};
        float4v acc1 = {0.f, 0.f, 0.f, 0.f};
        {
            half8 a0 = *(const half8*)(&Hc[l15 * LDSK + 0 * 32 + l4 * 8]);
            half8 a1 = *(const half8*)(&Hc[l15 * LDSK + 1 * 32 + l4 * 8]);
            half8 a2 = *(const half8*)(&Hc[l15 * LDSK + 2 * 32 + l4 * 8]);
            half8 a3 = *(const half8*)(&Hc[l15 * LDSK + 3 * 32 + l4 * 8]);
            half8 ax0 = *(const half8*)(&Hc[l15 * LDSK + 8 * 32 + l4 * 8]);
            half8 ax1 = *(const half8*)(&Hc[l15 * LDSK + 9 * 32 + l4 * 8]);
            acc0 = __builtin_amdgcn_mfma_f32_16x16x32_f16(a0, wl2v[(tlA*8+0)*64+lane], acc0, 0, 0, 0);
            acc1 = __builtin_amdgcn_mfma_f32_16x16x32_f16(a0, wl2v[(tlB*8+0)*64+lane], acc1, 0, 0, 0);
            acc0 = __builtin_amdgcn_mfma_f32_16x16x32_f16(a1, wl2v[(tlA*8+1)*64+lane], acc0, 0, 0, 0);
            acc1 = __builtin_amdgcn_mfma_f32_16x16x32_f16(a1, wl2v[(tlB*8+1)*64+lane], acc1, 0, 0, 0);
            acc0 = __builtin_amdgcn_mfma_f32_16x16x32_f16(a2, wl2v[(tlA*8+2)*64+lane], acc0, 0, 0, 0);
            acc1 = __builtin_amdgcn_mfma_f32_16x16x32_f16(a2, wl2v[(tlB*8+2)*64+lane], acc1, 0, 0, 0);
            acc0 = __builtin_amdgcn_mfma_f32_16x16x32_f16(a3, wl2v[(tlA*8+3)*64+lane], acc0, 0, 0, 0);
            acc1 = __builtin_amdgcn_mfma_f32_16x16x32_f16(a3, wl2v[(tlB*8+3)*64+lane], acc1, 0, 0, 0);
            acc0 = __builtin_amdgcn_mfma_f32_16x16x32_f16(ax0, wA8, acc0, 0, 0, 0);
            acc0 = __builtin_amdgcn_mfma_f32_16x16x32_f16(ax1, wA9, acc0, 0, 0, 0);
            acc1 = __builtin_amdgcn_mfma_f32_16x16x32_f16(ax0, wB8, acc1, 0, 0, 0);
            acc1 = __builtin_amdgcn_mfma_f32_16x16x32_f16(ax1, wB9, acc1, 0, 0, 0);
        }

        // --- deferred h2 ds_write (loads completed under part-1) ---
        if (!roleH1 && j > 0) {
            *(u64*)(&Hc[sb * LDSK + HN + sk * 8]) = q0;
            *(u64*)(&Hc[sb * LDSK + HN + sk * 8 + 4]) = q1;
        }
        __syncthreads();   // B1b: h2 staged

        // --- MFMA part-2: K = h2 (ks4..7), 8 MFMA ---
        {
            half8 a4 = *(const half8*)(&Hc[l15 * LDSK + 4 * 32 + l4 * 8]);
            half8 a5 = *(const half8*)(&Hc[l15 * LDSK + 5 * 32 + l4 * 8]);
            half8 a6 = *(const half8*)(&Hc[l15 * LDSK + 6 * 32 + l4 * 8]);
            half8 a7 = *(const half8*)(&Hc[l15 * LDSK + 7 * 32 + l4 * 8]);
            acc0 = __builtin_amdgcn_mfma_f32_16x16x32_f16(a4, wl2v[(tlA*8+4)*64+lane], acc0, 0, 0, 0);
            acc1 = __builtin_amdgcn_mfma_f32_16x16x32_f16(a4, wl2v[(tlB*8+4)*64+lane], acc1, 0, 0, 0);
            acc0 = __builtin_amdgcn_mfma_f32_16x16x32_f16(a5, wl2v[(tlA*8+5)*64+lane], acc0, 0, 0, 0);
            acc1 = __builtin_amdgcn_mfma_f32_16x16x32_f16(a5, wl2v[(tlB*8+5)*64+lane], acc1, 0, 0, 0);
            acc0 = __builtin_amdgcn_mfma_f32_16x16x32_f16(a6, wl2v[(tlA*8+6)*64+lane], acc0, 0, 0, 0);
            acc1 = __builtin_amdgcn_mfma_f32_16x16x32_f16(a6, wl2v[(tlB*8+6)*64+lane], acc1, 0, 0, 0);
            acc0 = __builtin_amdgcn_mfma_f32_16x16x32_f16(a7, wl2v[(tlA*8+7)*64+lane], acc0, 0, 0, 0);
            acc1 = __builtin_amdgcn_mfma_f32_16x16x32_f16(a7, wl2v[(tlB*8+7)*64+lane], acc1, 0, 0, 0);
            #pragma unroll
            for (int rg = 0; rg < 4; ++rg) {
                gb[(l4 * 4 + rg) * GBS2 + tlA * 16 + l15] = acc0[rg];
                gb[(l4 * 4 + rg) * GBS2 + tlB * 16 + l15] = acc1[rg];
            }
        }
        __syncthreads();   // B2: gb ready; Hc MFMA reads done

        // --- issue x(i,j+1) load early (hides under epilogue) ---
        u64 xv = 0;
        const bool doX = USE_XB && (t < 256) && (j + 1 < GN);
        if (doX)
            xv = *(const u64*)(xb + ((size_t)(cellidx + 1)) * (BN * CN)
                               + (t >> 4) * CN + (t & 15) * 4);

        // --- epilogue: LSTM pointwise for (eb, units u2,u2+1) ---
        {
            float g0[4], g1[4];
            #pragma unroll
            for (int q = 0; q < 4; ++q) {
                g0[q] = gb[eb * GBS2 + q * 64 + u2]     + blds[q * 64 + u2];
                g1[q] = gb[eb * GBS2 + q * 64 + u2 + 1] + blds[q * 64 + u2 + 1];
            }
            const int hu = ub * 64 + u2;         // unit within 128
            float cp0, cp1;
            if (dd == 0) {
                cp0 = 0.f; cp1 = 0.f;
                if (i > 0) {
                    const u64 cq = __hip_atomic_load(
                        (const u64*)(cmail + ((size_t)((((i - 1) & 1) * GN + j) * BN
                                     + eb)) * HN + hu),
                        __ATOMIC_RELAXED, __HIP_MEMORY_SCOPE_AGENT);
                    union { u64 q; float f[2]; } cu; cu.q = cq;
                    cp0 = cu.f[0]; cp1 = cu.f[1];
                }
            } else {
                cp0 = c2r0; cp1 = c2r1;
            }
            const float c0 = fsig(g0[1]) * cp0 + fsig(g0[0]) * ftanh(g0[2]);
            const float c1 = fsig(g1[1]) * cp1 + fsig(g1[0]) * ftanh(g1[2]);
            const float h0 = fsig(g0[3]) * ftanh(c0);
            const float h1 = fsig(g1[3]) * ftanh(c1);
            union { unsigned int u; _Float16 f[2]; } hp;
            hp.f[0] = (_Float16)h0; hp.f[1] = (_Float16)h1;

            if (dd == 0) {
                union { u64 q; float f[2]; } cn; cn.f[0] = c0; cn.f[1] = c1;
                __hip_atomic_store(
                    (u64*)(cmail + ((size_t)(((i & 1) * GN + j) * BN + eb)) * HN + hu),
                    cn.q, __ATOMIC_RELAXED, __HIP_MEMORY_SCOPE_AGENT);
            } else {
                c2r0 = c0; c2r1 = c1;
            }
            __hip_atomic_store(
                (unsigned int*)(hbuf + ((size_t)cellidx) * (BN * KH)
                                + eb * KH + dd * HN + hu),
                hp.u, __ATOMIC_RELAXED, __HIP_MEMORY_SCOPE_AGENT);
        }

        // --- x(i,j+1) ds_write (load issued above) ---
        if (doX)
            *(u64*)(&Hc[(t >> 4) * LDSK + KH + (t & 15) * 4]) = xv;
        if (!USE_XB && (j + 1 < GN)) {
            #pragma unroll
            for (int r = 0; r < 2; ++r) {
                const int e = t + r * 512;
                const int b2 = e >> 6, c = e & 63;
                Hc[b2 * LDSK + KH + c] =
                    (_Float16)x[(size_t)(b2 * 64 + c) * 4096 + i * 64 + (j + 1)];
            }
        }

        // --- per-wave drain + per-wave flag increment (no trailing barrier;
        //     next step's B1a orders the LDS writes for readers) ---
        asm volatile("s_waitcnt vmcnt(0)" ::: "memory");
        if ((t & 63) == 0)
            __hip_atomic_fetch_add((dd == 0 ? flag1 : flag2) + cellidx, 1,
                                   __ATOMIC_RELAXED, __HIP_MEMORY_SCOPE_AGENT);
    }
}

// ---------------- fallback (round-1 kernel, fp32, launch-per-diagonal) -------
constexpr int KCH = 32;
constexpr int NCH = KTOT / KCH;

__device__ __forceinline__ float sigmoidf_(float z) {
    return 1.f / (1.f + expf(-z));
}

__global__ __launch_bounds__(256, 1) void diag_kernel(
    const float* __restrict__ x, const float* __restrict__ Wih,
    const float* __restrict__ Whh, const float* __restrict__ bih,
    const float* __restrict__ bhh, float* __restrict__ out,
    float* __restrict__ cbuf, int d)
{
    __shared__ float HcF[BN][KTOT];
    __shared__ float Wch[KCH][257];
    const int cell = blockIdx.x >> 2;
    const int slice = blockIdx.x & 3;
    const int dd = slice >> 1;
    const int h0 = (slice & 1) * 64;
    const int i0 = (d > GN - 1) ? (d - (GN - 1)) : 0;
    const int i = i0 + cell;
    const int j = d - i;
    const int t = threadIdx.x;
    for (int e = t; e < BN * KTOT; e += 256) {
        const int b = e / KTOT, k = e - b * KTOT;
        float v;
        if (k < HN)      v = (i > 0) ? out[((b * KH + k) * GN + (i - 1)) * GN + j] : 0.f;
        else if (k < KH) v = (j > 0) ? out[((b * KH + k) * GN + i) * GN + (j - 1)] : 0.f;
        else             v = x[((b * CN + (k - KH)) * GN + i) * GN + j];
        HcF[b][k] = v;
    }
    const int h = t & 63, bg = t >> 6;
    const int grow = dd * 4 * HN + bg * HN + h0 + h;
    float acc[4][4];
    #pragma unroll
    for (int qq = 0; qq < 4; ++qq)
        #pragma unroll
        for (int bb = 0; bb < 4; ++bb) acc[qq][bb] = 0.f;
    for (int kb = 0; kb < NCH; ++kb) {
        const int kbase = kb * KCH;
        __syncthreads();
        const float* src = (kbase < KH) ? (Whh + (size_t)grow * KH + kbase)
                                        : (Wih + (size_t)grow * CN + (kbase - KH));
        #pragma unroll
        for (int k4 = 0; k4 < KCH / 4; ++k4) {
            const float4 w = *(const float4*)(src + k4 * 4);
            Wch[k4 * 4 + 0][t] = w.x; Wch[k4 * 4 + 1][t] = w.y;
            Wch[k4 * 4 + 2][t] = w.z; Wch[k4 * 4 + 3][t] = w.w;
        }
        __syncthreads();
        #pragma unroll 8
        for (int kk = 0; kk < KCH; ++kk) {
            const float w0 = Wch[kk][0 * 64 + h], w1 = Wch[kk][1 * 64 + h];
            const float w2 = Wch[kk][2 * 64 + h], w3 = Wch[kk][3 * 64 + h];
            #pragma unroll
            for (int bb = 0; bb < 4; ++bb) {
                const float hv = HcF[bg * 4 + bb][kbase + kk];
                acc[0][bb] = fmaf(w0, hv, acc[0][bb]);
                acc[1][bb] = fmaf(w1, hv, acc[1][bb]);
                acc[2][bb] = fmaf(w2, hv, acc[2][bb]);
                acc[3][bb] = fmaf(w3, hv, acc[3][bb]);
            }
        }
    }
    const int hu = h0 + h;
    float bias[4];
    #pragma unroll
    for (int qq = 0; qq < 4; ++qq) {
        const int gidx = dd * 4 * HN + qq * HN + hu;
        bias[qq] = bih[gidx] + bhh[gidx];
    }
    float* cptr = (dd == 0) ? (cbuf + (size_t)j * BN * HN)
                            : (cbuf + (size_t)GN * BN * HN + (size_t)i * BN * HN);
    const bool has_prev = (dd == 0) ? (i > 0) : (j > 0);
    #pragma unroll
    for (int bb = 0; bb < 4; ++bb) {
        const int b = bg * 4 + bb;
        const float gi = sigmoidf_(acc[0][bb] + bias[0]);
        const float gf = sigmoidf_(acc[1][bb] + bias[1]);
        const float gg = tanhf(acc[2][bb] + bias[2]);
        const float go = sigmoidf_(acc[3][bb] + bias[3]);
        const float cp = has_prev ? cptr[b * HN + hu] : 0.f;
        const float c = gf * cp + gi * gg;
        cptr[b * HN + hu] = c;
        out[((b * KH + dd * HN + hu) * GN + i) * GN + j] = go * tanhf(c);
    }
}

} // anonymous namespace

extern "C" void kernel_launch(void* const* d_in, const int* in_sizes, int n_in,
                              void* d_out, int out_size, void* d_ws, size_t ws_size,
                              hipStream_t stream) {
    const float* x   = (const float*)d_in[0];
    const float* Wih = (const float*)d_in[1];
    const float* Whh = (const float*)d_in[2];
    const float* bih = (const float*)d_in[3];
    const float* bhh = (const float*)d_in[4];
    float* out = (float*)d_out;

    const size_t HB_BYTES = (size_t)GN * GN * BN * KH * 2;        // 8 MB
    const size_t WF_BYTES = (size_t)640 * 64 * 8 * 2;             // 655 KB
    const size_t CM_BYTES = (size_t)2 * GN * BN * HN * 4;         // 1 MB
    const size_t FL_BYTES = (size_t)GN * GN * 4;                  // 16 KB
    const size_t XB_BYTES = (size_t)GN * GN * BN * CN * 2;        // 8 MB
    const size_t NEED_MIN  = HB_BYTES + WF_BYTES + CM_BYTES + 2 * FL_BYTES;
    const size_t NEED_FULL = NEED_MIN + XB_BYTES;

    if (ws_size >= NEED_MIN) {
        char* p = (char*)d_ws;
        _Float16* hbuf  = (_Float16*)p;                 p += HB_BYTES;
        _Float16* wfp   = (_Float16*)p;                 p += WF_BYTES;
        float*    cmail = (float*)p;                    p += CM_BYTES;
        int*      flag1 = (int*)p;                      p += FL_BYTES;
        int*      flag2 = (int*)p;                      p += FL_BYTES;
        _Float16* xbp   = (_Float16*)p;                 // only if NEED_FULL fits

        hipMemsetAsync(flag1, 0, 2 * FL_BYTES, stream);

        if (ws_size >= NEED_FULL) {
            hipLaunchKernelGGL(prep_kernel, dim3(640 + BN * GN), dim3(256), 0,
                               stream, Wih, Whh, wfp, x, xbp);
            void* args[] = { (void*)&wfp, (void*)&xbp, (void*)&x, (void*)&bih,
                             (void*)&bhh, (void*)&hbuf, (void*)&cmail,
                             (void*)&flag1, (void*)&flag2 };
            hipLaunchCooperativeKernel((const void*)grid_lstm_rowq<true>,
                                       dim3(256), dim3(512), args, 0, stream);
        } else {
            hipLaunchKernelGGL(prep_kernel, dim3(640), dim3(256), 0,
                               stream, Wih, Whh, wfp, x, xbp);
            void* args[] = { (void*)&wfp, (void*)&xbp, (void*)&x, (void*)&bih,
                             (void*)&bhh, (void*)&hbuf, (void*)&cmail,
                             (void*)&flag1, (void*)&flag2 };
            hipLaunchCooperativeKernel((const void*)grid_lstm_rowq<false>,
                                       dim3(256), dim3(512), args, 0, stream);
        }
        hipLaunchKernelGGL(out_kernel, dim3(BN * GN), dim3(256), 0, stream,
                           hbuf, out);
    } else {
        float* cbuf = (float*)d_ws;
        for (int d = 0; d < 2 * GN - 1; ++d) {
            const int i0 = (d > GN - 1) ? (d - (GN - 1)) : 0;
            const int i1 = (d < GN - 1) ? d : (GN - 1);
            const int nc = i1 - i0 + 1;
            hipLaunchKernelGGL(diag_kernel, dim3(nc * 4), dim3(256), 0, stream,
                               x, Wih, Whh, bih, bhh, out, cbuf, d);
        }
    }
}

// Round 14
// 460.618 us; speedup vs baseline: 1.0239x; 1.0239x over previous
//
#include <hip/hip_runtime.h>
#include <math.h>

namespace {

constexpr int BN = 16;      // batch
constexpr int CN = 64;      // input channels
constexpr int HN = 128;     // hidden
constexpr int GN = 64;      // grid dims
constexpr int KH = 2 * HN;          // 256
constexpr int KTOT = KH + CN;       // 320
constexpr int LDSK = 328;           // Hc stride (fp16 elems)
constexpr int GBS2 = 260;           // gb stride (fp32)

typedef _Float16 half8 __attribute__((ext_vector_type(8)));
typedef float float4v __attribute__((ext_vector_type(4)));
typedef unsigned long long u64;

// fast transcendentals (v_exp_f32 based) for the sweep epilogue
__device__ __forceinline__ float fsig(float z) {
    return 1.f / (1.f + __expf(-z));
}
__device__ __forceinline__ float ftanh(float z) {
    return 1.f - 2.f / (__expf(2.f * z) + 1.f);
}

// ---------------- merged prep: wprep (blk<640) + xconv (blk>=640) -------------
__global__ __launch_bounds__(256) void prep_kernel(
    const float* __restrict__ Wih,    // [2,512,64]
    const float* __restrict__ Whh,    // [2,512,256]
    _Float16* __restrict__ wf,        // [640][64][8]
    const float* __restrict__ x,      // [B,C,G,G]
    _Float16* __restrict__ xb)        // [G,G,B,C]
{
    const int blk = blockIdx.x;
    if (blk < 640) {
        const int t = threadIdx.x;
        if (t < 64) {
            const int nt = blk / 10, ks = blk - nt * 10;
            const int lane = t;
            const int dd = nt >> 5;
            const int gr = (nt & 31) * 16 + (lane & 15);    // gate row 0..511
            const int k0 = ks * 32 + (lane >> 4) * 8;
            _Float16* dst = wf + ((size_t)blk * 64 + lane) * 8;
            #pragma unroll
            for (int e = 0; e < 8; ++e) {
                const int k = k0 + e;
                const float v = (k < KH)
                    ? Whh[((size_t)(dd * 512 + gr)) * KH + k]
                    : Wih[((size_t)(dd * 512 + gr)) * CN + (k - KH)];
                dst[e] = (_Float16)v;
            }
        }
    } else {
        __shared__ float tile[CN][GN + 1];
        const int bb = blk - 640;
        const int b = bb >> 6;
        const int i = bb & 63;
        const int t = threadIdx.x;
        const int tj = t & 63, tc = t >> 6;
        for (int c0 = 0; c0 < CN; c0 += 4) {
            const int c = c0 + tc;
            tile[c][tj] = x[((size_t)(b * CN + c) * GN + i) * GN + tj];
        }
        __syncthreads();
        const int wc = t & 63, wj = t >> 6;
        for (int j0 = 0; j0 < GN; j0 += 4) {
            const int j = j0 + wj;
            xb[((size_t)(i * GN + j) * BN + b) * CN + wc] = (_Float16)tile[wc][j];
        }
    }
}

// ---------------- row-quad persistent sweep (r12-proven structure) ------------
// 256 blocks x 512 threads = 64 rows x 4 slices (dd, ub). Block owns row i.
// R14: out-transpose folded into the sweep tail. Each block wrote its own
// channel slice [dd*128+ub*64, +64) of row i to hbuf; after the j loop it
// reads that slice back (agent loads), transposes through the dead weight
// LDS (131 KB), and writes out as 256B-contiguous per-thread segments.
// Removes the separate out_kernel launch from the critical path; early rows
// transpose while later rows still sweep.
template <bool USE_XB>
__global__ __launch_bounds__(512, 1) void grid_lstm_rowq(
    const _Float16* __restrict__ wf,   // [640][64][8]
    const _Float16* __restrict__ xb,   // [G,G,B,C] (USE_XB)
    const float* __restrict__ x,       // [B,C,G,G] (!USE_XB)
    const float* __restrict__ bih,     // [2,512]
    const float* __restrict__ bhh,     // [2,512]
    _Float16* __restrict__ hbuf,       // [G,G,B,256]
    float* __restrict__ cmail,         // [2][G(j)][B][H] fp32 ring over i
    int* __restrict__ flag1,           // [G,G] h1 ready (target 16)
    int* __restrict__ flag2,           // [G,G] h2 ready (target 16)
    float* __restrict__ outp)          // [B,256,G,G]
{
    __shared__ __align__(16) _Float16 Wl2[16 * 8 * 64 * 8];  // 131072 B
    __shared__ __align__(16) _Float16 Hc[BN * LDSK];         // 10496 B
    __shared__ __align__(16) float gb[BN * GBS2];            // 16640 B
    __shared__ float blds[256];                              // 1024 B

    const int blk = blockIdx.x;
    const int i  = blk & 63;              // grid row (row-quad shares XCD)
    const int s  = blk >> 6;
    const int dd = s >> 1;                // grid-LSTM dim
    const int ub = s & 1;                 // unit half

    const int t = threadIdx.x;
    const int lane = t & 63;
    const int wv = t >> 6;                // wave 0..7
    const int l15 = lane & 15;
    const int l4 = lane >> 4;

    const half8* wfv = (const half8*)wf;
    half8* wl2v = (half8*)Wl2;

    // --- one-time: stage Whh fragments (ks 0..7) into LDS, fragment-major ---
    for (int e = t; e < 16 * 8 * 64; e += 512) {
        const int ln = e & 63, ks = (e >> 6) & 7, tl = e >> 9;
        const int q = tl >> 2, w = tl & 3;
        const int nt = dd * 32 + q * 8 + ub * 4 + w;
        wl2v[e] = wfv[(size_t)(nt * 10 + ks) * 64 + ln];
    }
    // --- one-time: Wih fragments (ks 8,9) into registers ---
    const int tlA = 2 * wv, tlB = 2 * wv + 1;
    const int ntA = dd * 32 + (tlA >> 2) * 8 + ub * 4 + (tlA & 3);
    const int ntB = dd * 32 + (tlB >> 2) * 8 + ub * 4 + (tlB & 3);
    const half8 wA8 = wfv[(size_t)(ntA * 10 + 8) * 64 + lane];
    const half8 wA9 = wfv[(size_t)(ntA * 10 + 9) * 64 + lane];
    const half8 wB8 = wfv[(size_t)(ntB * 10 + 8) * 64 + lane];
    const half8 wB9 = wfv[(size_t)(ntB * 10 + 9) * 64 + lane];
    // --- one-time: biases (local col = q*64 + uu) ---
    if (t < 256) {
        const int q = t >> 6, uu = t & 63;
        const int gr = dd * 512 + q * 128 + ub * 64 + uu;
        blds[t] = bih[gr] + bhh[gr];
    }
    // staging role (split): sb = batch, sk = 16B chunk within 128 fp16
    const int sb = (t & 255) >> 4;
    const int sk = (t & 15);
    const bool roleH1 = (t < 256);
    // epilogue role: batch eb, unit pair u2, u2+1
    const int eb = t >> 5;
    const int u2 = (t & 31) * 2;
    float c2r0 = 0.f, c2r1 = 0.f;        // dim1 c-state (dd==1 blocks)

    // --- prologue: stage x(i,0) ---
    if (USE_XB) {
        if (t < 256)
            *(u64*)(&Hc[(t >> 4) * LDSK + KH + (t & 15) * 4]) =
                *(const u64*)(xb + ((size_t)(i * GN)) * (BN * CN)
                              + (t >> 4) * CN + (t & 15) * 4);
    } else {
        #pragma unroll
        for (int r = 0; r < 2; ++r) {
            const int e = t + r * 512;
            const int b2 = e >> 6, c = e & 63;
            Hc[b2 * LDSK + KH + c] =
                (_Float16)x[(size_t)(b2 * 64 + c) * 4096 + i * 64];
        }
    }
    __syncthreads();

    for (int j = 0; j < GN; ++j) {
        const int cellidx = i * GN + j;

        // --- split-role staging: h1 written now; h2 loads issued, write deferred
        u64 q0 = 0, q1 = 0;
        if (roleH1) {
            if (i > 0) {
                const int* fp = flag1 + cellidx - GN;
                int it = 0;
                while (__hip_atomic_load(fp, __ATOMIC_RELAXED,
                                         __HIP_MEMORY_SCOPE_AGENT) < 16) {
                    __builtin_amdgcn_s_sleep(1);
                    if (++it > (1 << 24)) break;   // failsafe
                }
                const u64* src = (const u64*)(hbuf
                    + ((size_t)(cellidx - GN)) * (BN * KH) + sb * KH + sk * 8);
                q0 = __hip_atomic_load(src, __ATOMIC_RELAXED,
                                       __HIP_MEMORY_SCOPE_AGENT);
                q1 = __hip_atomic_load(src + 1, __ATOMIC_RELAXED,
                                       __HIP_MEMORY_SCOPE_AGENT);
            }
            *(u64*)(&Hc[sb * LDSK + sk * 8]) = q0;
            *(u64*)(&Hc[sb * LDSK + sk * 8 + 4]) = q1;
        } else {
            if (j > 0) {
                const int* fp = flag2 + cellidx - 1;
                int it = 0;
                while (__hip_atomic_load(fp, __ATOMIC_RELAXED,
                                         __HIP_MEMORY_SCOPE_AGENT) < 16) {
                    __builtin_amdgcn_s_sleep(1);
                    if (++it > (1 << 24)) break;
                }
                const u64* src = (const u64*)(hbuf
                    + ((size_t)(cellidx - 1)) * (BN * KH)
                    + sb * KH + HN + sk * 8);
                q0 = __hip_atomic_load(src, __ATOMIC_RELAXED,
                                       __HIP_MEMORY_SCOPE_AGENT);
                q1 = __hip_atomic_load(src + 1, __ATOMIC_RELAXED,
                                       __HIP_MEMORY_SCOPE_AGENT);
                // ds_write deferred to after MFMA part-1 (loads fly under it)
            } else {
                *(u64*)(&Hc[sb * LDSK + HN + sk * 8]) = 0ull;
                *(u64*)(&Hc[sb * LDSK + HN + sk * 8 + 4]) = 0ull;
            }
        }
        __syncthreads();   // B1a: h1 + x (+ h2 zeros at j==0) staged

        // --- MFMA part-1: K = h1 (ks0..3) + x (ks8,9), 12 MFMA ---
        float4v acc0 = {0.f, 0.f, 0.f, 0.f};
        float4v acc1 = {0.f, 0.f, 0.f, 0.f};
        {
            half8 a0 = *(const half8*)(&Hc[l15 * LDSK + 0 * 32 + l4 * 8]);
            half8 a1 = *(const half8*)(&Hc[l15 * LDSK + 1 * 32 + l4 * 8]);
            half8 a2 = *(const half8*)(&Hc[l15 * LDSK + 2 * 32 + l4 * 8]);
            half8 a3 = *(const half8*)(&Hc[l15 * LDSK + 3 * 32 + l4 * 8]);
            half8 ax0 = *(const half8*)(&Hc[l15 * LDSK + 8 * 32 + l4 * 8]);
            half8 ax1 = *(const half8*)(&Hc[l15 * LDSK + 9 * 32 + l4 * 8]);
            acc0 = __builtin_amdgcn_mfma_f32_16x16x32_f16(a0, wl2v[(tlA*8+0)*64+lane], acc0, 0, 0, 0);
            acc1 = __builtin_amdgcn_mfma_f32_16x16x32_f16(a0, wl2v[(tlB*8+0)*64+lane], acc1, 0, 0, 0);
            acc0 = __builtin_amdgcn_mfma_f32_16x16x32_f16(a1, wl2v[(tlA*8+1)*64+lane], acc0, 0, 0, 0);
            acc1 = __builtin_amdgcn_mfma_f32_16x16x32_f16(a1, wl2v[(tlB*8+1)*64+lane], acc1, 0, 0, 0);
            acc0 = __builtin_amdgcn_mfma_f32_16x16x32_f16(a2, wl2v[(tlA*8+2)*64+lane], acc0, 0, 0, 0);
            acc1 = __builtin_amdgcn_mfma_f32_16x16x32_f16(a2, wl2v[(tlB*8+2)*64+lane], acc1, 0, 0, 0);
            acc0 = __builtin_amdgcn_mfma_f32_16x16x32_f16(a3, wl2v[(tlA*8+3)*64+lane], acc0, 0, 0, 0);
            acc1 = __builtin_amdgcn_mfma_f32_16x16x32_f16(a3, wl2v[(tlB*8+3)*64+lane], acc1, 0, 0, 0);
            acc0 = __builtin_amdgcn_mfma_f32_16x16x32_f16(ax0, wA8, acc0, 0, 0, 0);
            acc0 = __builtin_amdgcn_mfma_f32_16x16x32_f16(ax1, wA9, acc0, 0, 0, 0);
            acc1 = __builtin_amdgcn_mfma_f32_16x16x32_f16(ax0, wB8, acc1, 0, 0, 0);
            acc1 = __builtin_amdgcn_mfma_f32_16x16x32_f16(ax1, wB9, acc1, 0, 0, 0);
        }

        // --- deferred h2 ds_write (loads completed under part-1) ---
        if (!roleH1 && j > 0) {
            *(u64*)(&Hc[sb * LDSK + HN + sk * 8]) = q0;
            *(u64*)(&Hc[sb * LDSK + HN + sk * 8 + 4]) = q1;
        }
        __syncthreads();   // B1b: h2 staged

        // --- MFMA part-2: K = h2 (ks4..7), 8 MFMA ---
        {
            half8 a4 = *(const half8*)(&Hc[l15 * LDSK + 4 * 32 + l4 * 8]);
            half8 a5 = *(const half8*)(&Hc[l15 * LDSK + 5 * 32 + l4 * 8]);
            half8 a6 = *(const half8*)(&Hc[l15 * LDSK + 6 * 32 + l4 * 8]);
            half8 a7 = *(const half8*)(&Hc[l15 * LDSK + 7 * 32 + l4 * 8]);
            acc0 = __builtin_amdgcn_mfma_f32_16x16x32_f16(a4, wl2v[(tlA*8+4)*64+lane], acc0, 0, 0, 0);
            acc1 = __builtin_amdgcn_mfma_f32_16x16x32_f16(a4, wl2v[(tlB*8+4)*64+lane], acc1, 0, 0, 0);
            acc0 = __builtin_amdgcn_mfma_f32_16x16x32_f16(a5, wl2v[(tlA*8+5)*64+lane], acc0, 0, 0, 0);
            acc1 = __builtin_amdgcn_mfma_f32_16x16x32_f16(a5, wl2v[(tlB*8+5)*64+lane], acc1, 0, 0, 0);
            acc0 = __builtin_amdgcn_mfma_f32_16x16x32_f16(a6, wl2v[(tlA*8+6)*64+lane], acc0, 0, 0, 0);
            acc1 = __builtin_amdgcn_mfma_f32_16x16x32_f16(a6, wl2v[(tlB*8+6)*64+lane], acc1, 0, 0, 0);
            acc0 = __builtin_amdgcn_mfma_f32_16x16x32_f16(a7, wl2v[(tlA*8+7)*64+lane], acc0, 0, 0, 0);
            acc1 = __builtin_amdgcn_mfma_f32_16x16x32_f16(a7, wl2v[(tlB*8+7)*64+lane], acc1, 0, 0, 0);
            #pragma unroll
            for (int rg = 0; rg < 4; ++rg) {
                gb[(l4 * 4 + rg) * GBS2 + tlA * 16 + l15] = acc0[rg];
                gb[(l4 * 4 + rg) * GBS2 + tlB * 16 + l15] = acc1[rg];
            }
        }
        __syncthreads();   // B2: gb ready; Hc MFMA reads done

        // --- issue x(i,j+1) load early (hides under epilogue) ---
        u64 xv = 0;
        const bool doX = USE_XB && (t < 256) && (j + 1 < GN);
        if (doX)
            xv = *(const u64*)(xb + ((size_t)(cellidx + 1)) * (BN * CN)
                               + (t >> 4) * CN + (t & 15) * 4);

        // --- epilogue: LSTM pointwise for (eb, units u2,u2+1) ---
        {
            float g0[4], g1[4];
            #pragma unroll
            for (int q = 0; q < 4; ++q) {
                g0[q] = gb[eb * GBS2 + q * 64 + u2]     + blds[q * 64 + u2];
                g1[q] = gb[eb * GBS2 + q * 64 + u2 + 1] + blds[q * 64 + u2 + 1];
            }
            const int hu = ub * 64 + u2;         // unit within 128
            float cp0, cp1;
            if (dd == 0) {
                cp0 = 0.f; cp1 = 0.f;
                if (i > 0) {
                    const u64 cq = __hip_atomic_load(
                        (const u64*)(cmail + ((size_t)((((i - 1) & 1) * GN + j) * BN
                                     + eb)) * HN + hu),
                        __ATOMIC_RELAXED, __HIP_MEMORY_SCOPE_AGENT);
                    union { u64 q; float f[2]; } cu; cu.q = cq;
                    cp0 = cu.f[0]; cp1 = cu.f[1];
                }
            } else {
                cp0 = c2r0; cp1 = c2r1;
            }
            const float c0 = fsig(g0[1]) * cp0 + fsig(g0[0]) * ftanh(g0[2]);
            const float c1 = fsig(g1[1]) * cp1 + fsig(g1[0]) * ftanh(g1[2]);
            const float h0 = fsig(g0[3]) * ftanh(c0);
            const float h1 = fsig(g1[3]) * ftanh(c1);
            union { unsigned int u; _Float16 f[2]; } hp;
            hp.f[0] = (_Float16)h0; hp.f[1] = (_Float16)h1;

            if (dd == 0) {
                union { u64 q; float f[2]; } cn; cn.f[0] = c0; cn.f[1] = c1;
                __hip_atomic_store(
                    (u64*)(cmail + ((size_t)(((i & 1) * GN + j) * BN + eb)) * HN + hu),
                    cn.q, __ATOMIC_RELAXED, __HIP_MEMORY_SCOPE_AGENT);
            } else {
                c2r0 = c0; c2r1 = c1;
            }
            __hip_atomic_store(
                (unsigned int*)(hbuf + ((size_t)cellidx) * (BN * KH)
                                + eb * KH + dd * HN + hu),
                hp.u, __ATOMIC_RELAXED, __HIP_MEMORY_SCOPE_AGENT);
        }

        // --- x(i,j+1) ds_write (load issued above) ---
        if (doX)
            *(u64*)(&Hc[(t >> 4) * LDSK + KH + (t & 15) * 4]) = xv;
        if (!USE_XB && (j + 1 < GN)) {
            #pragma unroll
            for (int r = 0; r < 2; ++r) {
                const int e = t + r * 512;
                const int b2 = e >> 6, c = e & 63;
                Hc[b2 * LDSK + KH + c] =
                    (_Float16)x[(size_t)(b2 * 64 + c) * 4096 + i * 64 + (j + 1)];
            }
        }

        // --- per-wave drain + per-wave flag increment (no trailing barrier;
        //     next step's B1a orders the LDS writes for readers) ---
        asm volatile("s_waitcnt vmcnt(0)" ::: "memory");
        if ((t & 63) == 0)
            __hip_atomic_fetch_add((dd == 0 ? flag1 : flag2) + cellidx, 1,
                                   __ATOMIC_RELAXED, __HIP_MEMORY_SCOPE_AGENT);
    }

    // ================= R14: in-sweep output transpose =================
    // This block wrote hbuf[i][j][b][dd*128+ub*64 .. +64) for all j,b.
    // Read it back (agent loads; own stores drained + MALL-coherent),
    // transpose via the dead weight-LDS, write out 256B/thread contiguous.
    __syncthreads();                       // all waves past last Wl2 use
    _Float16* tbuf = (_Float16*)Wl2;       // [16 b][64 ch][64 j] = 131072 B
    for (int e = t; e < 16384; e += 512) { // 64 j x 16 b x 16 u64-chunks
        const int j = e >> 8;
        const int r = e & 255;
        const int b = r >> 4, k8 = r & 15;
        const u64 v = __hip_atomic_load(
            (const u64*)(hbuf + ((size_t)(i * GN + j)) * (BN * KH)
                         + b * KH + dd * HN + ub * 64 + k8 * 4),
            __ATOMIC_RELAXED, __HIP_MEMORY_SCOPE_AGENT);
        union { u64 q; _Float16 f[4]; } u; u.q = v;
        #pragma unroll
        for (int c = 0; c < 4; ++c)
            tbuf[(b * 64 + k8 * 4 + c) * 64 + j] = u.f[c];
    }
    __syncthreads();
    for (int p = t; p < 1024; p += 512) {  // (b, ch) pairs, 2 per thread
        const int b = p >> 6, ch = p & 63;
        const int gch = dd * HN + ub * 64 + ch;
        float* op = outp + ((size_t)(b * KH + gch) * GN + i) * GN;
        const u64* src = (const u64*)(tbuf + (b * 64 + ch) * 64);
        #pragma unroll
        for (int jj = 0; jj < 16; ++jj) {  // 4 fp16 -> float4 per iter
            union { u64 q; _Float16 f[4]; } u; u.q = src[jj];
            float4 o;
            o.x = (float)u.f[0]; o.y = (float)u.f[1];
            o.z = (float)u.f[2]; o.w = (float)u.f[3];
            *(float4*)(op + jj * 4) = o;
        }
    }
}

// ---------------- fallback (round-1 kernel, fp32, launch-per-diagonal) -------
constexpr int KCH = 32;
constexpr int NCH = KTOT / KCH;

__device__ __forceinline__ float sigmoidf_(float z) {
    return 1.f / (1.f + expf(-z));
}

__global__ __launch_bounds__(256, 1) void diag_kernel(
    const float* __restrict__ x, const float* __restrict__ Wih,
    const float* __restrict__ Whh, const float* __restrict__ bih,
    const float* __restrict__ bhh, float* __restrict__ out,
    float* __restrict__ cbuf, int d)
{
    __shared__ float HcF[BN][KTOT];
    __shared__ float Wch[KCH][257];
    const int cell = blockIdx.x >> 2;
    const int slice = blockIdx.x & 3;
    const int dd = slice >> 1;
    const int h0 = (slice & 1) * 64;
    const int i0 = (d > GN - 1) ? (d - (GN - 1)) : 0;
    const int i = i0 + cell;
    const int j = d - i;
    const int t = threadIdx.x;
    for (int e = t; e < BN * KTOT; e += 256) {
        const int b = e / KTOT, k = e - b * KTOT;
        float v;
        if (k < HN)      v = (i > 0) ? out[((b * KH + k) * GN + (i - 1)) * GN + j] : 0.f;
        else if (k < KH) v = (j > 0) ? out[((b * KH + k) * GN + i) * GN + (j - 1)] : 0.f;
        else             v = x[((b * CN + (k - KH)) * GN + i) * GN + j];
        HcF[b][k] = v;
    }
    const int h = t & 63, bg = t >> 6;
    const int grow = dd * 4 * HN + bg * HN + h0 + h;
    float acc[4][4];
    #pragma unroll
    for (int qq = 0; qq < 4; ++qq)
        #pragma unroll
        for (int bb = 0; bb < 4; ++bb) acc[qq][bb] = 0.f;
    for (int kb = 0; kb < NCH; ++kb) {
        const int kbase = kb * KCH;
        __syncthreads();
        const float* src = (kbase < KH) ? (Whh + (size_t)grow * KH + kbase)
                                        : (Wih + (size_t)grow * CN + (kbase - KH));
        #pragma unroll
        for (int k4 = 0; k4 < KCH / 4; ++k4) {
            const float4 w = *(const float4*)(src + k4 * 4);
            Wch[k4 * 4 + 0][t] = w.x; Wch[k4 * 4 + 1][t] = w.y;
            Wch[k4 * 4 + 2][t] = w.z; Wch[k4 * 4 + 3][t] = w.w;
        }
        __syncthreads();
        #pragma unroll 8
        for (int kk = 0; kk < KCH; ++kk) {
            const float w0 = Wch[kk][0 * 64 + h], w1 = Wch[kk][1 * 64 + h];
            const float w2 = Wch[kk][2 * 64 + h], w3 = Wch[kk][3 * 64 + h];
            #pragma unroll
            for (int bb = 0; bb < 4; ++bb) {
                const float hv = HcF[bg * 4 + bb][kbase + kk];
                acc[0][bb] = fmaf(w0, hv, acc[0][bb]);
                acc[1][bb] = fmaf(w1, hv, acc[1][bb]);
                acc[2][bb] = fmaf(w2, hv, acc[2][bb]);
                acc[3][bb] = fmaf(w3, hv, acc[3][bb]);
            }
        }
    }
    const int hu = h0 + h;
    float bias[4];
    #pragma unroll
    for (int qq = 0; qq < 4; ++qq) {
        const int gidx = dd * 4 * HN + qq * HN + hu;
        bias[qq] = bih[gidx] + bhh[gidx];
    }
    float* cptr = (dd == 0) ? (cbuf + (size_t)j * BN * HN)
                            : (cbuf + (size_t)GN * BN * HN + (size_t)i * BN * HN);
    const bool has_prev = (dd == 0) ? (i > 0) : (j > 0);
    #pragma unroll
    for (int bb = 0; bb < 4; ++bb) {
        const int b = bg * 4 + bb;
        const float gi = sigmoidf_(acc[0][bb] + bias[0]);
        const float gf = sigmoidf_(acc[1][bb] + bias[1]);
        const float gg = tanhf(acc[2][bb] + bias[2]);
        const float go = sigmoidf_(acc[3][bb] + bias[3]);
        const float cp = has_prev ? cptr[b * HN + hu] : 0.f;
        const float c = gf * cp + gi * gg;
        cptr[b * HN + hu] = c;
        out[((b * KH + dd * HN + hu) * GN + i) * GN + j] = go * tanhf(c);
    }
}

} // anonymous namespace

extern "C" void kernel_launch(void* const* d_in, const int* in_sizes, int n_in,
                              void* d_out, int out_size, void* d_ws, size_t ws_size,
                              hipStream_t stream) {
    const float* x   = (const float*)d_in[0];
    const float* Wih = (const float*)d_in[1];
    const float* Whh = (const float*)d_in[2];
    const float* bih = (const float*)d_in[3];
    const float* bhh = (const float*)d_in[4];
    float* out = (float*)d_out;

    const size_t HB_BYTES = (size_t)GN * GN * BN * KH * 2;        // 8 MB
    const size_t WF_BYTES = (size_t)640 * 64 * 8 * 2;             // 655 KB
    const size_t CM_BYTES = (size_t)2 * GN * BN * HN * 4;         // 1 MB
    const size_t FL_BYTES = (size_t)GN * GN * 4;                  // 16 KB
    const size_t XB_BYTES = (size_t)GN * GN * BN * CN * 2;        // 8 MB
    const size_t NEED_MIN  = HB_BYTES + WF_BYTES + CM_BYTES + 2 * FL_BYTES;
    const size_t NEED_FULL = NEED_MIN + XB_BYTES;

    if (ws_size >= NEED_MIN) {
        char* p = (char*)d_ws;
        _Float16* hbuf  = (_Float16*)p;                 p += HB_BYTES;
        _Float16* wfp   = (_Float16*)p;                 p += WF_BYTES;
        float*    cmail = (float*)p;                    p += CM_BYTES;
        int*      flag1 = (int*)p;                      p += FL_BYTES;
        int*      flag2 = (int*)p;                      p += FL_BYTES;
        _Float16* xbp   = (_Float16*)p;                 // only if NEED_FULL fits

        hipMemsetAsync(flag1, 0, 2 * FL_BYTES, stream);

        if (ws_size >= NEED_FULL) {
            hipLaunchKernelGGL(prep_kernel, dim3(640 + BN * GN), dim3(256), 0,
                               stream, Wih, Whh, wfp, x, xbp);
            void* args[] = { (void*)&wfp, (void*)&xbp, (void*)&x, (void*)&bih,
                             (void*)&bhh, (void*)&hbuf, (void*)&cmail,
                             (void*)&flag1, (void*)&flag2, (void*)&out };
            hipLaunchCooperativeKernel((const void*)grid_lstm_rowq<true>,
                                       dim3(256), dim3(512), args, 0, stream);
        } else {
            hipLaunchKernelGGL(prep_kernel, dim3(640), dim3(256), 0,
                               stream, Wih, Whh, wfp, x, xbp);
            void* args[] = { (void*)&wfp, (void*)&xbp, (void*)&x, (void*)&bih,
                             (void*)&bhh, (void*)&hbuf, (void*)&cmail,
                             (void*)&flag1, (void*)&flag2, (void*)&out };
            hipLaunchCooperativeKernel((const void*)grid_lstm_rowq<false>,
                                       dim3(256), dim3(512), args, 0, stream);
        }
    } else {
        float* cbuf = (float*)d_ws;
        for (int d = 0; d < 2 * GN - 1; ++d) {
            const int i0 = (d > GN - 1) ? (d - (GN - 1)) : 0;
            const int i1 = (d < GN - 1) ? d : (GN - 1);
            const int nc = i1 - i0 + 1;
            hipLaunchKernelGGL(diag_kernel, dim3(nc * 4), dim3(256), 0, stream,
                               x, Wih, Whh, bih, bhh, out, cbuf, d);
        }
    }
}